// Round 8
// baseline (15.556 us; speedup 1.0000x reference)
//
#include <hip/hip_runtime.h>
#include <math.h>

#define NN 256
#define PP 32640             // N*(N-1)/2
#define HH 64
#define BB 32
#define SPLIT 32             // scan blocks per batch
#define NF4 (PP / 4)         // 8160 float4 per row
#define F4_PER (NF4 / SPLIT) // 255 float4 per chunk

// Two dispatches (R6/R7 proved in-kernel cross-block sync costs more than a
// second dispatch; graph inter-dispatch gap < 1us).
//
// Collapsed network (verified absmax 0.0 in R1-R7): GCN graph is the complete
// digraph + self-loops => norm = 1/256, conv outputs node-independent:
//   sum(deg) = 2*count(dec==1); #(deg==0) = 256 - popcount(touched mask)
//   g1=relu((f@W1)/256+b1); g2=relu(g1@W2+b2); g3=relu(g2@W3+b3)
//   hm=relu([g3,g3,e0,e1,1]@We1+be1); out=sigmoid(hm@We2+be2) twice.

// ---------------------------------------------------------------------------
// Kernel 1: per-(batch,chunk) scan, 1024 blocks x 256 threads, no atomics.
// One float4 of dec + ind per thread. Partials: 8 mask words + 1 count per
// block, plus packed edge features (e0,e1) captured at find-time (the finder
// already holds dec[cur] in registers -> no dependent x[cur] load later).
// ---------------------------------------------------------------------------
__global__ __launch_bounds__(256) void gnn_scan(
    const float* __restrict__ x,
    unsigned int* __restrict__ ws_mask,  // [BB*SPLIT][8]
    int* __restrict__ ws_cnt,            // [BB*SPLIT]
    unsigned int* __restrict__ ws_e01)   // [BB]
{
    const int blk   = blockIdx.x;
    const int b     = blk >> 5;          // / SPLIT
    const int chunk = blk & (SPLIT - 1);
    const int tid   = threadIdx.x;
    const int lane  = tid & 63;
    const int w     = tid >> 6;

    __shared__ unsigned char touched[NN];
    __shared__ int wcnt[4];
    touched[tid] = 0;
    __syncthreads();

    const float*  decp = x + (size_t)b * (2 * PP);
    const float4* dec4 = (const float4*)decp;
    const float4* ind4 = (const float4*)(decp + PP);

    int cnt = 0;
    if (tid < F4_PER) {
        const int q  = chunk * F4_PER + tid;
        float4 d  = dec4[q];
        float4 iv = ind4[q];
        const int p0 = q * 4;

        // invert triu_indices once: O(i) = i*(511-i)/2
        int i = (int)((511.0f - sqrtf(261121.0f - 8.0f * (float)p0)) * 0.5f);
        while (i * (511 - i) / 2 > p0) --i;
        while ((i + 1) * (510 - i) / 2 <= p0) ++i;
        int rowStart = i * (511 - i) / 2;

        float dv[4]  = {d.x, d.y, d.z, d.w};
        float ivv[4] = {iv.x, iv.y, iv.z, iv.w};
        #pragma unroll
        for (int u = 0; u < 4; ++u) {
            const int p = p0 + u;
            while (p - rowStart >= 255 - i) { ++i; rowStart = i * (511 - i) / 2; }
            if (ivv[u] > 0.5f) {                 // one-hot: single writer
                ws_e01[b] = (dv[u] == 1.0f ? 1u : 0u) | (dv[u] != 0.5f ? 2u : 0u);
            }
            if (dv[u] == 1.0f) {
                const int j = i + 1 + (p - rowStart);
                touched[i] = 1;                  // racy-identical: benign
                touched[j] = 1;
                ++cnt;
            }
        }
    }
    __syncthreads();

    unsigned long long m = __ballot(touched[tid] != 0);
    if (lane == 0) {
        ws_mask[blk * 8 + w * 2 + 0] = (unsigned int)m;
        ws_mask[blk * 8 + w * 2 + 1] = (unsigned int)(m >> 32);
    }
    #pragma unroll
    for (int off = 32; off > 0; off >>= 1) cnt += __shfl_down(cnt, off);
    if (lane == 0) wcnt[w] = cnt;
    __syncthreads();
    if (tid == 0) ws_cnt[blk] = wcnt[0] + wcnt[1] + wcnt[2] + wcnt[3];
}

// ---------------------------------------------------------------------------
// Kernel 2: ONE WAVE per batch (32 blocks x 64 threads). Zero __syncthreads:
// mask OR-reduce + count-sum via shuffle butterflies; matvec chain via
// __shfl(g, k) broadcast (v_readlane at constant k) with coalesced weight
// column loads; lane o owns output column o throughout.
// ---------------------------------------------------------------------------
__global__ __launch_bounds__(64) void gnn_epilogue(
    const float* __restrict__ W1, const float* __restrict__ b1,
    const float* __restrict__ W2, const float* __restrict__ b2,
    const float* __restrict__ W3, const float* __restrict__ b3,
    const float* __restrict__ We1, const float* __restrict__ be1,
    const float* __restrict__ We2, const float* __restrict__ be2,
    const unsigned int* __restrict__ ws_mask,
    const int* __restrict__ ws_cnt,
    const unsigned int* __restrict__ ws_e01,
    float* __restrict__ out)
{
    const int b = blockIdx.x;
    const int o = threadIdx.x;           // 0..63, one wave

    // ---- touched-mask OR-reduce: lane l holds uint4 = chunk l>>1, words (l&1)*4.. ----
    const uint4* mp = (const uint4*)(ws_mask + (size_t)b * (SPLIT * 8));
    uint4 m = mp[o];                      // 64 lanes x 16B = all 256 words
    #pragma unroll
    for (int off = 2; off < 64; off <<= 1) {
        m.x |= __shfl_xor(m.x, off);
        m.y |= __shfl_xor(m.y, off);
        m.z |= __shfl_xor(m.z, off);
        m.w |= __shfl_xor(m.w, off);
    }
    // lane0: OR of words 0-3 over all chunks; lane1: words 4-7
    int p = __popc(m.x) + __popc(m.y) + __popc(m.z) + __popc(m.w);
    p += __shfl_xor(p, 1);
    const int pop = __shfl(p, 0);

    // ---- count sum over 32 chunks ----
    int c = (o < SPLIT) ? ws_cnt[b * SPLIT + o] : 0;
    #pragma unroll
    for (int off = 1; off < 32; off <<= 1) c += __shfl_xor(c, off);
    const int scnt = __shfl(c, 0);

    const unsigned int se = ws_e01[b];    // same address -> broadcast load
    const float e0 = (float)(se & 1u);
    const float e1 = (float)((se >> 1) & 1u);

    const float f0 = (float)(2 * scnt) * (1.0f / 255.0f);
    const float f1 = (float)(NN - pop);

    // g1 = relu((f @ W1)/256 + b1)
    float g = fmaxf((f0 * W1[o] + f1 * W1[HH + o] + 2.0f * W1[2 * HH + o])
                    * (1.0f / 256.0f) + b1[o], 0.0f);

    // g2 = relu(g1 @ W2 + b2)
    float acc = b2[o];
    #pragma unroll
    for (int k = 0; k < HH; ++k) acc += __shfl(g, k) * W2[k * HH + o];
    g = fmaxf(acc, 0.0f);

    // g3 = relu(g2 @ W3 + b3)
    acc = b3[o];
    #pragma unroll
    for (int k = 0; k < HH; ++k) acc += __shfl(g, k) * W3[k * HH + o];
    g = fmaxf(acc, 0.0f);

    // hm = relu([g3,g3,e0,e1,1] @ We1 + be1)
    acc = be1[o] + e0 * We1[128 * HH + o] + e1 * We1[129 * HH + o] + We1[130 * HH + o];
    #pragma unroll
    for (int k = 0; k < HH; ++k)
        acc += __shfl(g, k) * (We1[k * HH + o] + We1[(HH + k) * HH + o]);
    const float hm = fmaxf(acc, 0.0f);

    float contrib = hm * We2[o];
    #pragma unroll
    for (int off = 32; off > 0; off >>= 1)
        contrib += __shfl_down(contrib, off);

    if (o == 0) {
        const float sig = 1.0f / (1.0f + expf(-(contrib + be2[0])));
        out[b * 2 + 0] = sig;
        out[b * 2 + 1] = sig;
    }
}

extern "C" void kernel_launch(void* const* d_in, const int* in_sizes, int n_in,
                              void* d_out, int out_size, void* d_ws, size_t ws_size,
                              hipStream_t stream) {
    const float* x   = (const float*)d_in[0];
    const float* W1  = (const float*)d_in[1];
    const float* b1  = (const float*)d_in[2];
    const float* W2  = (const float*)d_in[3];
    const float* b2  = (const float*)d_in[4];
    const float* W3  = (const float*)d_in[5];
    const float* b3  = (const float*)d_in[6];
    const float* We1 = (const float*)d_in[7];
    const float* be1 = (const float*)d_in[8];
    const float* We2 = (const float*)d_in[9];
    const float* be2 = (const float*)d_in[10];
    float* out = (float*)d_out;

    unsigned int* ws_mask = (unsigned int*)d_ws;                 // 32 KB
    int* ws_cnt = (int*)(ws_mask + (size_t)BB * SPLIT * 8);     // 4 KB
    unsigned int* ws_e01 = (unsigned int*)(ws_cnt + BB * SPLIT); // 128 B

    gnn_scan<<<BB * SPLIT, 256, 0, stream>>>(x, ws_mask, ws_cnt, ws_e01);
    gnn_epilogue<<<BB, 64, 0, stream>>>(W1, b1, W2, b2, W3, b3,
                                        We1, be1, We2, be2,
                                        ws_mask, ws_cnt, ws_e01, out);
}

// Round 9
// 13.256 us; speedup vs baseline: 1.1735x; 1.1735x over previous
//
#include <hip/hip_runtime.h>
#include <math.h>

#define NN 256
#define PP 32640             // N*(N-1)/2
#define HH 64
#define BB 32
#define CHUNKS 16            // scan blocks per batch
#define NBLK (BB * CHUNKS)   // 512 scan blocks
#define NF4 (PP / 4)         // 8160 float4 per row
#define F4C (NF4 / CHUNKS)   // 510 float4 per chunk

// Two dispatches (R5/R6/R7 proved 1-dispatch alternatives lose: fused 32-block
// scan +1.4us, coop sync +30us, spin handshake +1.2us).
//
// Collapsed network (verified absmax 0.0 in R1-R8): GCN graph is the complete
// digraph + self-loops => norm = 1/256, conv outputs node-independent:
//   sum(deg) = 2*count(dec==1); #(deg==0) = 256 - popcount(touched mask)
//   g1=relu((f@W1)/256+b1); g2=relu(g1@W2+b2); g3=relu(g2@W3+b3)
//   hm=relu([g3,g3,e0,e1,1]@We1+be1); out=sigmoid(hm@We2+be2) twice.

// ---------------------------------------------------------------------------
// Kernel 1: per-(batch,chunk) scan, 512 blocks x 256 threads, no atomics.
// Two float4 of dec + ind per thread. Partials per block: 8 mask words +
// 1 count; edge features (e0,e1) packed at find-time (finder already holds
// dec[cur] in a register -> epilogue needs no dependent x[cur] load).
// ---------------------------------------------------------------------------
__global__ __launch_bounds__(256) void gnn_scan(
    const float* __restrict__ x,
    unsigned int* __restrict__ ws_mask,  // [NBLK][8]
    int* __restrict__ ws_cnt,            // [NBLK]
    unsigned int* __restrict__ ws_e01)   // [BB]
{
    const int blk   = blockIdx.x;
    const int b     = blk >> 4;          // / CHUNKS
    const int chunk = blk & (CHUNKS - 1);
    const int tid   = threadIdx.x;
    const int lane  = tid & 63;
    const int w     = tid >> 6;

    __shared__ unsigned char touched[NN];
    __shared__ int wcnt[4];
    touched[tid] = 0;
    __syncthreads();

    const float*  decp = x + (size_t)b * (2 * PP);
    const float4* dec4 = (const float4*)decp;
    const float4* ind4 = (const float4*)(decp + PP);

    int cnt = 0;
    #pragma unroll
    for (int it = 0; it < 2; ++it) {
        const int qq = tid + it * 256;
        if (qq < F4C) {
            const int q  = chunk * F4C + qq;
            float4 d  = dec4[q];
            float4 iv = ind4[q];
            const int p0 = q * 4;

            // invert triu_indices once per float4: O(i) = i*(511-i)/2
            int i = (int)((511.0f - sqrtf(261121.0f - 8.0f * (float)p0)) * 0.5f);
            while (i * (511 - i) / 2 > p0) --i;
            while ((i + 1) * (510 - i) / 2 <= p0) ++i;
            int rowStart = i * (511 - i) / 2;

            float dv[4]  = {d.x, d.y, d.z, d.w};
            float ivv[4] = {iv.x, iv.y, iv.z, iv.w};
            #pragma unroll
            for (int u = 0; u < 4; ++u) {
                const int p = p0 + u;
                while (p - rowStart >= 255 - i) { ++i; rowStart = i * (511 - i) / 2; }
                if (ivv[u] > 0.5f) {             // one-hot: single writer grid-wide
                    ws_e01[b] = (dv[u] == 1.0f ? 1u : 0u) | (dv[u] != 0.5f ? 2u : 0u);
                }
                if (dv[u] == 1.0f) {
                    const int j = i + 1 + (p - rowStart);
                    touched[i] = 1;              // racy-identical: benign
                    touched[j] = 1;
                    ++cnt;
                }
            }
        }
    }
    __syncthreads();

    unsigned long long m = __ballot(touched[tid] != 0);
    if (lane == 0) {
        ws_mask[blk * 8 + w * 2 + 0] = (unsigned int)m;
        ws_mask[blk * 8 + w * 2 + 1] = (unsigned int)(m >> 32);
    }
    #pragma unroll
    for (int off = 32; off > 0; off >>= 1) cnt += __shfl_down(cnt, off);
    if (lane == 0) wcnt[w] = cnt;
    __syncthreads();
    if (tid == 0) ws_cnt[blk] = wcnt[0] + wcnt[1] + wcnt[2] + wcnt[3];
}

// ---------------------------------------------------------------------------
// Kernel 2: one block per batch, 256 threads (R4 structure — R8 disproved the
// single-wave variant). Weights prefetched into REGISTERS up front so the
// matvec chain never waits on global loads; partial reduce as R4; matvecs
// k-split over the 4 waves.
// ---------------------------------------------------------------------------
__global__ __launch_bounds__(256) void gnn_epilogue(
    const float* __restrict__ W1, const float* __restrict__ b1,
    const float* __restrict__ W2, const float* __restrict__ b2,
    const float* __restrict__ W3, const float* __restrict__ b3,
    const float* __restrict__ We1, const float* __restrict__ be1,
    const float* __restrict__ We2, const float* __restrict__ be2,
    const unsigned int* __restrict__ ws_mask,
    const int* __restrict__ ws_cnt,
    const unsigned int* __restrict__ ws_e01,
    float* __restrict__ out)
{
    const int b    = blockIdx.x;
    const int tid  = threadIdx.x;
    const int lane = tid & 63;
    const int w    = tid >> 6;

    __shared__ float gS[HH];
    __shared__ float pr[4][HH];
    __shared__ unsigned int mw[CHUNKS * 8];   // 128 words
    __shared__ int ic[CHUNKS];
    __shared__ int s_pop;

    // ---- register weight prefetch (independent loads, issue first) ----
    float w2r[16], w3r[16], war[16], wbr[16];
    #pragma unroll
    for (int kk = 0; kk < 16; ++kk) {
        w2r[kk] = W2 [(w * 16 + kk) * HH + lane];
        w3r[kk] = W3 [(w * 16 + kk) * HH + lane];
        war[kk] = We1[(w * 16 + kk) * HH + lane];
        wbr[kk] = We1[(64 + w * 16 + kk) * HH + lane];
    }
    float w1r0 = 0, w1r1 = 0, w1r2 = 0, b1r = 0, b2r = 0, b3r = 0, be1r = 0;
    float er0 = 0, er1 = 0, er2 = 0, we2r = 0;
    if (tid < HH) {
        w1r0 = W1[tid]; w1r1 = W1[HH + tid]; w1r2 = W1[2 * HH + tid];
        b1r = b1[tid]; b2r = b2[tid]; b3r = b3[tid]; be1r = be1[tid];
        er0 = We1[128 * HH + tid]; er1 = We1[129 * HH + tid];
        er2 = We1[130 * HH + tid]; we2r = We2[tid];
    }
    const float be2r = be2[0];

    // ---- partial loads ----
    if (tid == 0) s_pop = 0;
    if (tid < CHUNKS * 8) mw[tid] = ws_mask[b * (CHUNKS * 8) + tid];
    if (tid < CHUNKS) ic[tid] = ws_cnt[b * CHUNKS + tid];
    const unsigned int se = ws_e01[b];        // broadcast load
    __syncthreads();

    if (tid < 8) {
        unsigned int o = 0;
        #pragma unroll
        for (int c = 0; c < CHUNKS; ++c) o |= mw[c * 8 + tid];
        atomicAdd(&s_pop, __popc(o));
    }
    __syncthreads();

    int scnt = 0;
    #pragma unroll
    for (int c = 0; c < CHUNKS; ++c) scnt += ic[c];

    const float f0 = (float)(2 * scnt) * (1.0f / 255.0f);
    const float f1 = (float)(NN - s_pop);

    if (tid < HH) {
        float s = f0 * w1r0 + f1 * w1r1 + 2.0f * w1r2;
        gS[tid] = fmaxf(s * (1.0f / 256.0f) + b1r, 0.0f);
    }
    __syncthreads();

    {   // g2 = relu(g1 @ W2 + b2), k split over 4 waves
        float s = 0.0f;
        #pragma unroll
        for (int kk = 0; kk < 16; ++kk) s += gS[w * 16 + kk] * w2r[kk];
        pr[w][lane] = s;
    }
    __syncthreads();
    if (tid < HH)
        gS[tid] = fmaxf(pr[0][tid] + pr[1][tid] + pr[2][tid] + pr[3][tid] + b2r, 0.0f);
    __syncthreads();

    {   // g3 = relu(g2 @ W3 + b3)
        float s = 0.0f;
        #pragma unroll
        for (int kk = 0; kk < 16; ++kk) s += gS[w * 16 + kk] * w3r[kk];
        pr[w][lane] = s;
    }
    __syncthreads();
    if (tid < HH)
        gS[tid] = fmaxf(pr[0][tid] + pr[1][tid] + pr[2][tid] + pr[3][tid] + b3r, 0.0f);
    __syncthreads();

    {   // hm = relu([g3,g3,e0,e1,1] @ We1 + be1)
        float s = 0.0f;
        #pragma unroll
        for (int kk = 0; kk < 16; ++kk) s += gS[w * 16 + kk] * (war[kk] + wbr[kk]);
        pr[w][lane] = s;
    }
    __syncthreads();
    if (tid < HH) {   // exactly wave 0
        const float e0 = (float)(se & 1u);
        const float e1 = (float)((se >> 1) & 1u);
        float v = pr[0][tid] + pr[1][tid] + pr[2][tid] + pr[3][tid] + be1r
                + e0 * er0 + e1 * er1 + er2;
        v = fmaxf(v, 0.0f);

        float contrib = v * we2r;
        #pragma unroll
        for (int off = 32; off > 0; off >>= 1)
            contrib += __shfl_down(contrib, off);

        if (tid == 0) {
            const float sig = 1.0f / (1.0f + expf(-(contrib + be2r)));
            out[b * 2 + 0] = sig;
            out[b * 2 + 1] = sig;
        }
    }
}

extern "C" void kernel_launch(void* const* d_in, const int* in_sizes, int n_in,
                              void* d_out, int out_size, void* d_ws, size_t ws_size,
                              hipStream_t stream) {
    const float* x   = (const float*)d_in[0];
    const float* W1  = (const float*)d_in[1];
    const float* b1  = (const float*)d_in[2];
    const float* W2  = (const float*)d_in[3];
    const float* b2  = (const float*)d_in[4];
    const float* W3  = (const float*)d_in[5];
    const float* b3  = (const float*)d_in[6];
    const float* We1 = (const float*)d_in[7];
    const float* be1 = (const float*)d_in[8];
    const float* We2 = (const float*)d_in[9];
    const float* be2 = (const float*)d_in[10];
    float* out = (float*)d_out;

    unsigned int* ws_mask = (unsigned int*)d_ws;                  // 16 KB
    int* ws_cnt = (int*)(ws_mask + (size_t)NBLK * 8);             // 2 KB
    unsigned int* ws_e01 = (unsigned int*)(ws_cnt + NBLK);        // 128 B

    gnn_scan<<<NBLK, 256, 0, stream>>>(x, ws_mask, ws_cnt, ws_e01);
    gnn_epilogue<<<BB, 256, 0, stream>>>(W1, b1, W2, b2, W3, b3,
                                         We1, be1, We2, be2,
                                         ws_mask, ws_cnt, ws_e01, out);
}

// Round 10
// 13.012 us; speedup vs baseline: 1.1956x; 1.0188x over previous
//
#include <hip/hip_runtime.h>
#include <math.h>

#define NN 256
#define PP 32640             // N*(N-1)/2
#define HH 64
#define BB 32
#define CHUNKS 16            // scan blocks per batch
#define NBLK (BB * CHUNKS)   // 512 scan blocks
#define NF4 (PP / 4)         // 8160 float4 per row
#define F4C (NF4 / CHUNKS)   // 510 float4 per chunk

// Two dispatches (R5/R6/R7: all 1-dispatch alternatives lose — fused scan
// +1.4us, coop grid sync +30us, spin handshake +1.8us; graph gap < 1us).
//
// Collapsed network (verified absmax 0.0 R1-R9): GCN graph is the complete
// digraph + self-loops => norm = 1/256, conv outputs node-independent:
//   sum(deg) = 2*count(dec==1); #(deg==0) = 256 - popcount(touched mask)
//   g1=relu((f@W1)/256+b1); g2=relu(g1@W2+b2); g3=relu(g2@W3+b3)
//   hm=relu([g3,g3,e0,e1,1]@We1+be1); out=sigmoid(hm@We2+be2) twice.

// ---------------------------------------------------------------------------
// Kernel 1 (unchanged from R9): per-(batch,chunk) scan, 512 x 256, no atomics.
// ---------------------------------------------------------------------------
__global__ __launch_bounds__(256) void gnn_scan(
    const float* __restrict__ x,
    unsigned int* __restrict__ ws_mask,  // [NBLK][8]
    int* __restrict__ ws_cnt,            // [NBLK]
    unsigned int* __restrict__ ws_e01)   // [BB]
{
    const int blk   = blockIdx.x;
    const int b     = blk >> 4;          // / CHUNKS
    const int chunk = blk & (CHUNKS - 1);
    const int tid   = threadIdx.x;
    const int lane  = tid & 63;
    const int w     = tid >> 6;

    __shared__ unsigned char touched[NN];
    __shared__ int wcnt[4];
    touched[tid] = 0;
    __syncthreads();

    const float*  decp = x + (size_t)b * (2 * PP);
    const float4* dec4 = (const float4*)decp;
    const float4* ind4 = (const float4*)(decp + PP);

    int cnt = 0;
    #pragma unroll
    for (int it = 0; it < 2; ++it) {
        const int qq = tid + it * 256;
        if (qq < F4C) {
            const int q  = chunk * F4C + qq;
            float4 d  = dec4[q];
            float4 iv = ind4[q];
            const int p0 = q * 4;

            // invert triu_indices once per float4: O(i) = i*(511-i)/2
            int i = (int)((511.0f - sqrtf(261121.0f - 8.0f * (float)p0)) * 0.5f);
            while (i * (511 - i) / 2 > p0) --i;
            while ((i + 1) * (510 - i) / 2 <= p0) ++i;
            int rowStart = i * (511 - i) / 2;

            float dv[4]  = {d.x, d.y, d.z, d.w};
            float ivv[4] = {iv.x, iv.y, iv.z, iv.w};
            #pragma unroll
            for (int u = 0; u < 4; ++u) {
                const int p = p0 + u;
                while (p - rowStart >= 255 - i) { ++i; rowStart = i * (511 - i) / 2; }
                if (ivv[u] > 0.5f) {             // one-hot: single writer grid-wide
                    ws_e01[b] = (dv[u] == 1.0f ? 1u : 0u) | (dv[u] != 0.5f ? 2u : 0u);
                }
                if (dv[u] == 1.0f) {
                    const int j = i + 1 + (p - rowStart);
                    touched[i] = 1;              // racy-identical: benign
                    touched[j] = 1;
                    ++cnt;
                }
            }
        }
    }
    __syncthreads();

    unsigned long long m = __ballot(touched[tid] != 0);
    if (lane == 0) {
        ws_mask[blk * 8 + w * 2 + 0] = (unsigned int)m;
        ws_mask[blk * 8 + w * 2 + 1] = (unsigned int)(m >> 32);
    }
    #pragma unroll
    for (int off = 32; off > 0; off >>= 1) cnt += __shfl_down(cnt, off);
    if (lane == 0) wcnt[w] = cnt;
    __syncthreads();
    if (tid == 0) ws_cnt[blk] = wcnt[0] + wcnt[1] + wcnt[2] + wcnt[3];
}

// ---------------------------------------------------------------------------
// Kernel 2: one block per batch, 256 threads, 4-wave k-split matvecs (R9).
// NEW: partial reduction (pop, scnt, e01) done entirely in wave-0 registers
// via direct coalesced global loads + shfl_xor — no LDS staging, no atomics,
// two fewer __syncthreads; waves 1-3 go straight to weight prefetch.
// ---------------------------------------------------------------------------
__global__ __launch_bounds__(256) void gnn_epilogue(
    const float* __restrict__ W1, const float* __restrict__ b1,
    const float* __restrict__ W2, const float* __restrict__ b2,
    const float* __restrict__ W3, const float* __restrict__ b3,
    const float* __restrict__ We1, const float* __restrict__ be1,
    const float* __restrict__ We2, const float* __restrict__ be2,
    const unsigned int* __restrict__ ws_mask,
    const int* __restrict__ ws_cnt,
    const unsigned int* __restrict__ ws_e01,
    float* __restrict__ out)
{
    const int b    = blockIdx.x;
    const int tid  = threadIdx.x;
    const int lane = tid & 63;
    const int w    = tid >> 6;

    __shared__ float gS[HH];
    __shared__ float pr[4][HH];

    // ---- register weight prefetch (independent loads, issue first) ----
    float w2r[16], w3r[16], war[16], wbr[16];
    #pragma unroll
    for (int kk = 0; kk < 16; ++kk) {
        w2r[kk] = W2 [(w * 16 + kk) * HH + lane];
        w3r[kk] = W3 [(w * 16 + kk) * HH + lane];
        war[kk] = We1[(w * 16 + kk) * HH + lane];
        wbr[kk] = We1[(64 + w * 16 + kk) * HH + lane];
    }
    float b2r = b2[lane], b3r = b3[lane];
    float e0 = 0.0f, e1 = 0.0f, be1r = 0.0f, er0 = 0.0f, er1 = 0.0f,
          er2 = 0.0f, we2r = 0.0f, be2r = 0.0f;

    if (w == 0) {
        // ---- wave-0 register reduction of partials ----
        const unsigned int* mb = ws_mask + (size_t)b * (CHUNKS * 8);
        unsigned int m = mb[lane] | mb[64 + lane];   // chunks (lane>>3) and +8
        m |= __shfl_xor(m, 8);
        m |= __shfl_xor(m, 16);
        m |= __shfl_xor(m, 32);        // lane holds OR for word pos lane&7
        int pp = __popc(m);
        pp += __shfl_xor(pp, 1);
        pp += __shfl_xor(pp, 2);
        pp += __shfl_xor(pp, 4);       // sum of 8 distinct positions

        int c = ws_cnt[b * CHUNKS + (lane & 15)];
        c += __shfl_xor(c, 1); c += __shfl_xor(c, 2);
        c += __shfl_xor(c, 4); c += __shfl_xor(c, 8);

        const unsigned int se = ws_e01[b];          // broadcast load
        e0 = (float)(se & 1u);
        e1 = (float)((se >> 1) & 1u);

        be1r = be1[lane];
        er0 = We1[128 * HH + lane]; er1 = We1[129 * HH + lane];
        er2 = We1[130 * HH + lane]; we2r = We2[lane];
        be2r = be2[0];

        const float f0 = (float)(2 * c) * (1.0f / 255.0f);
        const float f1 = (float)(NN - pp);

        // g1 = relu((f @ W1)/256 + b1)
        float s = f0 * W1[lane] + f1 * W1[HH + lane] + 2.0f * W1[2 * HH + lane];
        gS[lane] = fmaxf(s * (1.0f / 256.0f) + b1[lane], 0.0f);
    }
    __syncthreads();

    {   // g2 = relu(g1 @ W2 + b2), k split over 4 waves
        float s = 0.0f;
        #pragma unroll
        for (int kk = 0; kk < 16; ++kk) s += gS[w * 16 + kk] * w2r[kk];
        pr[w][lane] = s;
    }
    __syncthreads();
    if (tid < HH)
        gS[tid] = fmaxf(pr[0][tid] + pr[1][tid] + pr[2][tid] + pr[3][tid] + b2r, 0.0f);
    __syncthreads();

    {   // g3 = relu(g2 @ W3 + b3)
        float s = 0.0f;
        #pragma unroll
        for (int kk = 0; kk < 16; ++kk) s += gS[w * 16 + kk] * w3r[kk];
        pr[w][lane] = s;
    }
    __syncthreads();
    if (tid < HH)
        gS[tid] = fmaxf(pr[0][tid] + pr[1][tid] + pr[2][tid] + pr[3][tid] + b3r, 0.0f);
    __syncthreads();

    {   // hm = relu([g3,g3,e0,e1,1] @ We1 + be1)
        float s = 0.0f;
        #pragma unroll
        for (int kk = 0; kk < 16; ++kk) s += gS[w * 16 + kk] * (war[kk] + wbr[kk]);
        pr[w][lane] = s;
    }
    __syncthreads();
    if (tid < HH) {   // exactly wave 0 (holds e0/e1/er*/we2r/be2r in registers)
        float v = pr[0][tid] + pr[1][tid] + pr[2][tid] + pr[3][tid] + be1r
                + e0 * er0 + e1 * er1 + er2;
        v = fmaxf(v, 0.0f);

        float contrib = v * we2r;
        #pragma unroll
        for (int off = 32; off > 0; off >>= 1)
            contrib += __shfl_down(contrib, off);

        if (tid == 0) {
            const float sig = 1.0f / (1.0f + expf(-(contrib + be2r)));
            out[b * 2 + 0] = sig;
            out[b * 2 + 1] = sig;
        }
    }
}

extern "C" void kernel_launch(void* const* d_in, const int* in_sizes, int n_in,
                              void* d_out, int out_size, void* d_ws, size_t ws_size,
                              hipStream_t stream) {
    const float* x   = (const float*)d_in[0];
    const float* W1  = (const float*)d_in[1];
    const float* b1  = (const float*)d_in[2];
    const float* W2  = (const float*)d_in[3];
    const float* b2  = (const float*)d_in[4];
    const float* W3  = (const float*)d_in[5];
    const float* b3  = (const float*)d_in[6];
    const float* We1 = (const float*)d_in[7];
    const float* be1 = (const float*)d_in[8];
    const float* We2 = (const float*)d_in[9];
    const float* be2 = (const float*)d_in[10];
    float* out = (float*)d_out;

    unsigned int* ws_mask = (unsigned int*)d_ws;                  // 16 KB
    int* ws_cnt = (int*)(ws_mask + (size_t)NBLK * 8);             // 2 KB
    unsigned int* ws_e01 = (unsigned int*)(ws_cnt + NBLK);        // 128 B

    gnn_scan<<<NBLK, 256, 0, stream>>>(x, ws_mask, ws_cnt, ws_e01);
    gnn_epilogue<<<BB, 256, 0, stream>>>(W1, b1, W2, b2, W3, b3,
                                         We1, be1, We2, be2,
                                         ws_mask, ws_cnt, ws_e01, out);
}